// Round 1
// baseline (2419.313 us; speedup 1.0000x reference)
//
#include <hip/hip_runtime.h>

// Problem constants (fixed shapes for this identifier)
#define N_ROWS 16384   // b*n = 4*4096
#define DIM    512
#define KCODES 8192

#define DECAYF 0.8f
#define RESIDF 0.2f    // float32(1.0 - 0.8) as JAX computes it (f64 then cast)
#define EPSF   1e-5f

// ---- d_out float offsets (outputs concatenated in return order) ----
#define OQ 0            // quantize_st    [16384,512]
#define OI 8388608      // ind            [16384]
#define OL 8404992      // commit_loss    [1]
#define OE 8404993      // new_embed      [8192,512]
#define OC 12599297     // new_cluster    [8192]
#define OA 12607489     // new_embed_avg  [8192,512]

// ---- workspace float offsets ----
#define WS_E2    0                  // [8192]
#define WS_BINS  8192               // [8192]
#define WS_LOSS  16384              // [1]
#define WS_TOTAL 16385              // [1]
#define WS_PV1   16400              // [4][16384] top-1 value per k-split
#define WS_PI1   (16400+65536)      // [4][16384] top-1 idx (int)
#define WS_PV2   (16400+131072)     // [4][16384] top-2 value
#define WS_PI2   (16400+196608)     // [4][16384] top-2 idx (int)
#define WS_IND   (16400+262144)     // [16384] final idx (int)

// ================= kernel 1a: e2[k] = sum(embed[k]^2) =================
__global__ void e2_kernel(const float* __restrict__ embed, float* __restrict__ ws) {
    int wid = threadIdx.x >> 6, lane = threadIdx.x & 63;
    int code = blockIdx.x * 4 + wid;
    const float4* row = (const float4*)(embed + code * DIM);
    float s = 0.f;
#pragma unroll
    for (int i = 0; i < 2; ++i) {
        float4 v = row[lane * 2 + i];
        s += v.x*v.x + v.y*v.y + v.z*v.z + v.w*v.w;
    }
#pragma unroll
    for (int off = 32; off; off >>= 1) s += __shfl_xor(s, off);
    if (lane == 0) ws[WS_E2 + code] = s;
}

// ============ kernel 1b: out_avg = 0.8 * embed_avg (re-init every call) ============
__global__ void avginit_kernel(const float* __restrict__ avg, float* __restrict__ out) {
    int i = blockIdx.x * blockDim.x + threadIdx.x;   // 1,048,576 threads * 4 elems
    float4 v = ((const float4*)avg)[i];
    int base = i * 4;                                 // OA region is only 4B-aligned
    out[OA + base + 0] = DECAYF * v.x;
    out[OA + base + 1] = DECAYF * v.y;
    out[OA + base + 2] = DECAYF * v.z;
    out[OA + base + 3] = DECAYF * v.w;
}

// ================= kernel 2: fused distance GEMM + top-2 argmin =================
// score(row,code) = e2[code] - 2*dot(x[row],embed[code])   (x2 const per row)
#define BM 128
#define BN 128
#define KD 16
#define KSPLIT 4
#define LDST 132   // 128 + 4 pad: keeps float4 alignment (132*4 % 16 == 0), 2-way banks

__global__ __launch_bounds__(256, 2) void dist_kernel(
        const float* __restrict__ x, const float* __restrict__ embed,
        float* __restrict__ ws) {
    __shared__ __align__(16) float xs[KD][LDST];
    __shared__ __align__(16) float es[KD][LDST];
    __shared__ float redv1[2][BM]; __shared__ int redi1[2][BM];
    __shared__ float redv2[2][BM]; __shared__ int redi2[2][BM];

    const int tid  = threadIdx.x;
    const int wid  = tid >> 6, lane = tid & 63;
    // waves tile the 16x16 thread grid as 2x2 blocks of 8x8 -> both LDS operand
    // reads have only 8 unique b128 addrs/wave at 32B stride = 2-way (free)
    const int tr = (wid >> 1) * 8 + (lane >> 3);   // 0..15 (8 rows each)
    const int tc = (wid &  1) * 8 + (lane &  7);   // 0..15 (8 cols each)
    const int rowbase = blockIdx.x * BM;
    const int kbase0  = blockIdx.y * (KCODES / KSPLIT);
    const int lrow = tid >> 2;          // loader: 0..63
    const int lc4  = (tid & 3) * 4;     // loader col: 0,4,8,12

    float best1[8], best2[8]; int bidx1[8], bidx2[8];
#pragma unroll
    for (int i = 0; i < 8; ++i) {
        best1[i] = 3.4e38f; best2[i] = 3.4e38f;
        bidx1[i] = 0x7fffffff; bidx2[i] = 0x7fffffff;
    }
    float acc[8][8];
#pragma unroll
    for (int i = 0; i < 8; ++i)
#pragma unroll
        for (int j = 0; j < 8; ++j) acc[i][j] = 0.f;

    const int NTILES = (KCODES / KSPLIT) / BN;  // 16
    const int NITER  = NTILES * 32;             // 32 d-chunks of 16

    float4 px0, px1, pe0, pe1;
    {   // prefetch iter 0
        const float* xg = x + (rowbase + lrow) * DIM + lc4;
        px0 = *(const float4*)xg;
        px1 = *(const float4*)(xg + 64 * DIM);
        const float* eg = embed + (kbase0 + lrow) * DIM + lc4;
        pe0 = *(const float4*)eg;
        pe1 = *(const float4*)(eg + 64 * DIM);
    }

    for (int iter = 0; iter < NITER; ++iter) {
        const int kt = iter >> 5;
        const int dc = iter & 31;
        __syncthreads();
        // store prefetched chunk to LDS transposed [d][row]
#pragma unroll
        for (int j = 0; j < 4; ++j) {
            xs[lc4 + j][lrow]      = ((const float*)&px0)[j];
            xs[lc4 + j][lrow + 64] = ((const float*)&px1)[j];
            es[lc4 + j][lrow]      = ((const float*)&pe0)[j];
            es[lc4 + j][lrow + 64] = ((const float*)&pe1)[j];
        }
        __syncthreads();
        if (iter + 1 < NITER) {   // prefetch next chunk (hides latency under FMAs)
            const int kt2 = (iter + 1) >> 5, dc2 = (iter + 1) & 31;
            const float* xg = x + (rowbase + lrow) * DIM + dc2 * KD + lc4;
            px0 = *(const float4*)xg;
            px1 = *(const float4*)(xg + 64 * DIM);
            const float* eg = embed + (kbase0 + kt2 * BN + lrow) * DIM + dc2 * KD + lc4;
            pe0 = *(const float4*)eg;
            pe1 = *(const float4*)(eg + 64 * DIM);
        }
#pragma unroll
        for (int dk = 0; dk < KD; ++dk) {
            float4 xa = *(const float4*)&xs[dk][tr * 8];
            float4 xb = *(const float4*)&xs[dk][tr * 8 + 4];
            float4 ea = *(const float4*)&es[dk][tc * 8];
            float4 eb = *(const float4*)&es[dk][tc * 8 + 4];
            float xv[8] = {xa.x, xa.y, xa.z, xa.w, xb.x, xb.y, xb.z, xb.w};
            float ev[8] = {ea.x, ea.y, ea.z, ea.w, eb.x, eb.y, eb.z, eb.w};
#pragma unroll
            for (int i = 0; i < 8; ++i)
#pragma unroll
                for (int j = 0; j < 8; ++j)
                    acc[i][j] += xv[i] * ev[j];
        }
        if (dc == 31) {   // k-tile epilogue: fold into per-thread top-2
            const int cbase = kbase0 + kt * BN + tc * 8;
            float e2v[8];
#pragma unroll
            for (int j = 0; j < 8; ++j) e2v[j] = ws[WS_E2 + cbase + j];
#pragma unroll
            for (int i = 0; i < 8; ++i) {
#pragma unroll
                for (int j = 0; j < 8; ++j) {
                    float v = e2v[j] - 2.f * acc[i][j];
                    int  ci = cbase + j;
                    bool lt1 = (v < best1[i]) || (v == best1[i] && ci < bidx1[i]);
                    bool lt2 = (v < best2[i]) || (v == best2[i] && ci < bidx2[i]);
                    if (lt1) { best2[i] = best1[i]; bidx2[i] = bidx1[i];
                               best1[i] = v; bidx1[i] = ci; }
                    else if (lt2) { best2[i] = v; bidx2[i] = ci; }
                    acc[i][j] = 0.f;
                }
            }
        }
    }

    // reduce top-2 across tc within wave (lane bits 1,2,4)
#pragma unroll
    for (int m = 1; m <= 4; m <<= 1) {
#pragma unroll
        for (int i = 0; i < 8; ++i) {
            float o1 = __shfl_xor(best1[i], m); int oi1 = __shfl_xor(bidx1[i], m);
            float o2 = __shfl_xor(best2[i], m); int oi2 = __shfl_xor(bidx2[i], m);
            bool o1lt = (o1 < best1[i]) || (o1 == best1[i] && oi1 < bidx1[i]);
            if (o1lt) {
                bool t = (o2 < best1[i]) || (o2 == best1[i] && oi2 < bidx1[i]);
                best2[i] = t ? o2 : best1[i]; bidx2[i] = t ? oi2 : bidx1[i];
                best1[i] = o1; bidx1[i] = oi1;
            } else {
                bool t = (o1 < best2[i]) || (o1 == best2[i] && oi1 < bidx2[i]);
                if (t) { best2[i] = o1; bidx2[i] = oi1; }
            }
        }
    }
    const int h = wid & 1;
    if ((lane & 7) == 0) {
#pragma unroll
        for (int i = 0; i < 8; ++i) {
            int r = tr * 8 + i;
            redv1[h][r] = best1[i]; redi1[h][r] = bidx1[i];
            redv2[h][r] = best2[i]; redi2[h][r] = bidx2[i];
        }
    }
    __syncthreads();
    if (tid < BM) {   // combine the two tc-halves, write per-split partials
        int r = tid;
        float a1 = redv1[0][r], a2 = redv2[0][r]; int i1 = redi1[0][r], i2 = redi2[0][r];
        float o1 = redv1[1][r], o2 = redv2[1][r]; int j1 = redi1[1][r], j2 = redi2[1][r];
        float b1, b2; int c1, c2;
        bool o1lt = (o1 < a1) || (o1 == a1 && j1 < i1);
        if (o1lt) {
            b1 = o1; c1 = j1;
            bool t = (o2 < a1) || (o2 == a1 && j2 < i1);
            b2 = t ? o2 : a1; c2 = t ? j2 : i1;
        } else {
            b1 = a1; c1 = i1;
            bool t = (o1 < a2) || (o1 == a2 && j1 < i2);
            b2 = t ? o1 : a2; c2 = t ? j1 : i2;
        }
        int p = blockIdx.y * N_ROWS + rowbase + r;
        ws[WS_PV1 + p] = b1; ((int*)ws)[WS_PI1 + p] = c1;
        ws[WS_PV2 + p] = b2; ((int*)ws)[WS_PI2 + p] = c2;
    }
}

// ====== kernel 2b: fp64 refine of 8 candidates/row -> exact first-min argmin ======
__global__ void refine_kernel(const float* __restrict__ x, const float* __restrict__ embed,
                              float* __restrict__ ws, float* __restrict__ out) {
    int wid = threadIdx.x >> 6, lane = threadIdx.x & 63;
    int row = blockIdx.x * 4 + wid;
    const float* xr = x + row * DIM;
    double bestv = 1e300; int besti = 0x7fffffff;
#pragma unroll
    for (int s = 0; s < 4; ++s) {
#pragma unroll
        for (int t = 0; t < 2; ++t) {
            int ci = ((const int*)ws)[(t ? WS_PI2 : WS_PI1) + s * N_ROWS + row];
            const float* er = embed + ci * DIM;
            double d = 0.0;
#pragma unroll
            for (int u = 0; u < 8; ++u) {
                double diff = (double)xr[lane * 8 + u] - (double)er[lane * 8 + u];
                d += diff * diff;
            }
#pragma unroll
            for (int off = 32; off; off >>= 1) d += __shfl_xor(d, off);
            if (d < bestv || (d == bestv && ci < besti)) { bestv = d; besti = ci; }
        }
    }
    if (lane == 0) {
        ((int*)ws)[WS_IND + row] = besti;
        out[OI + row] = (float)besti;   // harness reads outputs as float32
    }
}

// ===== kernel 3: gather quantize, commit-loss partial, scatter EMA sums =====
__global__ void gather_kernel(const float* __restrict__ x, const float* __restrict__ embed,
                              float* __restrict__ ws, float* __restrict__ out) {
    int tid = threadIdx.x;
    int rl  = tid >> 7;            // 2 rows per 256-thread block
    int c   = (tid & 127) * 4;
    int row = blockIdx.x * 2 + rl;
    int ind = ((const int*)ws)[WS_IND + row];
    float4 q  = *(const float4*)(embed + ind * DIM + c);
    float4 xv = *(const float4*)(x + row * DIM + c);
    float4 st;  // match ref rounding: x + (q - x)
    st.x = xv.x + (q.x - xv.x); st.y = xv.y + (q.y - xv.y);
    st.z = xv.z + (q.z - xv.z); st.w = xv.w + (q.w - xv.w);
    *(float4*)(out + OQ + row * DIM + c) = st;
    float dx = q.x - xv.x, dy = q.y - xv.y, dz = q.z - xv.z, dw = q.w - xv.w;
    float s = dx*dx + dy*dy + dz*dz + dw*dw;
#pragma unroll
    for (int off = 32; off; off >>= 1) s += __shfl_xor(s, off);
    __shared__ float ls[4];
    int wid = tid >> 6, lane = tid & 63;
    if (lane == 0) ls[wid] = s;
    __syncthreads();
    if (tid == 0) atomicAdd(ws + WS_LOSS, ls[0] + ls[1] + ls[2] + ls[3]);
    // EMA scatter: out_avg preset to 0.8*embed_avg, add 0.2*x (4B-aligned region -> scalar)
    atomicAdd(out + OA + ind * DIM + c + 0, RESIDF * xv.x);
    atomicAdd(out + OA + ind * DIM + c + 1, RESIDF * xv.y);
    atomicAdd(out + OA + ind * DIM + c + 2, RESIDF * xv.z);
    atomicAdd(out + OA + ind * DIM + c + 3, RESIDF * xv.w);
    if ((tid & 127) == 0) atomicAdd(ws + WS_BINS + ind, 1.0f);
}

// ===== kernel 4: new_cluster_size, total reduction, finalize loss =====
__global__ void cluster_kernel(const float* __restrict__ cs, float* __restrict__ ws,
                               float* __restrict__ out) {
    int k = blockIdx.x * 256 + threadIdx.x;
    float ncs = DECAYF * cs[k] + RESIDF * ws[WS_BINS + k];
    out[OC + k] = ncs;
    float s = ncs;
#pragma unroll
    for (int off = 32; off; off >>= 1) s += __shfl_xor(s, off);
    __shared__ float ls[4];
    int wid = threadIdx.x >> 6, lane = threadIdx.x & 63;
    if (lane == 0) ls[wid] = s;
    __syncthreads();
    if (threadIdx.x == 0) atomicAdd(ws + WS_TOTAL, ls[0] + ls[1] + ls[2] + ls[3]);
    if (k == 0) out[OL] = ws[WS_LOSS] / 8388608.0f;
}

// ===== kernel 5: new_embed = new_embed_avg / laplace-smoothed cluster sizes =====
__global__ void finalize_kernel(const float* __restrict__ ws, float* __restrict__ out) {
    int i = blockIdx.x * 256 + threadIdx.x;   // 1,048,576 threads * 4 elems
    int base = i * 4;
    int k = base >> 9;
    float total = ws[WS_TOTAL];
    float ncs = out[OC + k];
    float sm = (ncs + EPSF) / (total + (float)KCODES * EPSF) * total;
#pragma unroll
    for (int j = 0; j < 4; ++j) {
        float av = out[OA + base + j];
        out[OE + base + j] = av / sm;
    }
}

extern "C" void kernel_launch(void* const* d_in, const int* in_sizes, int n_in,
                              void* d_out, int out_size, void* d_ws, size_t ws_size,
                              hipStream_t stream) {
    const float* x     = (const float*)d_in[0];
    const float* embed = (const float*)d_in[1];
    const float* cs    = (const float*)d_in[2];
    const float* avg   = (const float*)d_in[3];
    float* out = (float*)d_out;
    float* ws  = (float*)d_ws;

    // zero bins + loss + total (contiguous floats 8192..16385) every call
    hipMemsetAsync((char*)d_ws + WS_BINS * 4, 0, (8192 + 2) * 4, stream);

    e2_kernel     <<<KCODES / 4, 256, 0, stream>>>(embed, ws);
    avginit_kernel<<<4096, 256, 0, stream>>>(avg, out);
    dist_kernel   <<<dim3(N_ROWS / BM, KSPLIT), 256, 0, stream>>>(x, embed, ws);
    refine_kernel <<<N_ROWS / 4, 256, 0, stream>>>(x, embed, ws, out);
    gather_kernel <<<N_ROWS / 2, 256, 0, stream>>>(x, embed, ws, out);
    cluster_kernel<<<KCODES / 256, 256, 0, stream>>>(cs, ws, out);
    finalize_kernel<<<4096, 256, 0, stream>>>(ws, out);
}

// Round 2
// 702.361 us; speedup vs baseline: 3.4445x; 3.4445x over previous
//
#include <hip/hip_runtime.h>

// Problem constants (fixed shapes for this identifier)
#define N_ROWS 16384   // b*n = 4*4096
#define DIM    512
#define KCODES 8192

#define DECAYF 0.8f
#define RESIDF 0.2f
#define EPSF   1e-5f

// ---- d_out float offsets (outputs concatenated in return order) ----
#define OQ 0            // quantize_st    [16384,512]  (scratch: Xs fp16 h|l, exactly fills it)
#define OI 8388608      // ind            [16384]
#define OL 8404992      // commit_loss    [1]
#define OE 8404993      // new_embed      [8192,512]   (scratch: Es fp16 h|l, 16B-realigned)
#define OC 12599297     // new_cluster    [8192]
#define OA 12607489     // new_embed_avg  [8192,512]

// ---- workspace float offsets ----
#define WS_E2    0                  // [8192]
#define WS_BINS  8192               // [8192]
#define WS_LOSS  16384              // [1]
#define WS_TOTAL 16385              // [1]
#define WS_PV1   16400              // [4][16384] top-1 value per k-split
#define WS_PI1   (16400+65536)      // [4][16384] top-1 idx (int)
#define WS_PV2   (16400+131072)     // [4][16384] top-2 value
#define WS_PI2   (16400+196608)     // [4][16384] top-2 idx (int)
#define WS_IND   (16400+262144)     // [16384] final idx (int)

typedef _Float16 half8 __attribute__((ext_vector_type(8)));
typedef float f32x4 __attribute__((ext_vector_type(4)));

__device__ __forceinline__ void ldg_lds16(const char* g, char* l) {
    __builtin_amdgcn_global_load_lds(
        (const __attribute__((address_space(1))) void*)g,
        (__attribute__((address_space(3))) void*)l, 16, 0, 0);
}

// ======= kernel 0a: split x (f32) -> Xs fp16 rows [512 h | 512 l] =======
__global__ void convx_kernel(const float* __restrict__ x, _Float16* __restrict__ xs) {
    int i = blockIdx.x * 256 + threadIdx.x;        // 1,048,576 threads, 8 elems each
    int row = i >> 6;
    int c8 = (i & 63) * 8;
    const float4* g = (const float4*)(x + row * DIM + c8);
    float4 v0 = g[0], v1 = g[1];
    float vv[8] = {v0.x, v0.y, v0.z, v0.w, v1.x, v1.y, v1.z, v1.w};
    half8 hv, lv;
#pragma unroll
    for (int j = 0; j < 8; ++j) {
        _Float16 h = (_Float16)vv[j];
        hv[j] = h;
        lv[j] = (_Float16)(vv[j] - (float)h);
    }
    *(half8*)(xs + row * 1024 + c8)       = hv;
    *(half8*)(xs + row * 1024 + 512 + c8) = lv;
}

// ======= kernel 0b: split embed (f32) -> Es fp16 rows [512 h | 512 l] =======
__global__ void conve_kernel(const float* __restrict__ e, _Float16* __restrict__ es) {
    int i = blockIdx.x * 256 + threadIdx.x;        // 524,288 threads
    int row = i >> 6;
    int c8 = (i & 63) * 8;
    const float4* g = (const float4*)(e + row * DIM + c8);
    float4 v0 = g[0], v1 = g[1];
    float vv[8] = {v0.x, v0.y, v0.z, v0.w, v1.x, v1.y, v1.z, v1.w};
    half8 hv, lv;
#pragma unroll
    for (int j = 0; j < 8; ++j) {
        _Float16 h = (_Float16)vv[j];
        hv[j] = h;
        lv[j] = (_Float16)(vv[j] - (float)h);
    }
    *(half8*)(es + row * 1024 + c8)       = hv;
    *(half8*)(es + row * 1024 + 512 + c8) = lv;
}

// ================= kernel 1a: e2[k] = sum(embed[k]^2), f32 exact =================
__global__ void e2_kernel(const float* __restrict__ embed, float* __restrict__ ws) {
    int wid = threadIdx.x >> 6, lane = threadIdx.x & 63;
    int code = blockIdx.x * 4 + wid;
    const float4* row = (const float4*)(embed + code * DIM);
    float s = 0.f;
#pragma unroll
    for (int i = 0; i < 2; ++i) {
        float4 v = row[lane * 2 + i];
        s += v.x*v.x + v.y*v.y + v.z*v.z + v.w*v.w;
    }
#pragma unroll
    for (int off = 32; off; off >>= 1) s += __shfl_xor(s, off);
    if (lane == 0) ws[WS_E2 + code] = s;
}

// ============ kernel 1b: out_avg = 0.8 * embed_avg (re-init every call) ============
__global__ void avginit_kernel(const float* __restrict__ avg, float* __restrict__ out) {
    int i = blockIdx.x * blockDim.x + threadIdx.x;
    float4 v = ((const float4*)avg)[i];
    int base = i * 4;                              // OA region only 4B-aligned
    out[OA + base + 0] = DECAYF * v.x;
    out[OA + base + 1] = DECAYF * v.y;
    out[OA + base + 2] = DECAYF * v.z;
    out[OA + base + 3] = DECAYF * v.w;
}

// ============ kernel 2: MFMA 3-pass fp16 distance GEMM + fused top-2/split ============
// 128x128 tile, 4 waves (2x2, each 64x64), BK=32, K=512, 16 col-tiles per block.
// LDS tiles: [128 rows][128B] where bytes 0-63 = h (32 fp16 of this K-step), 64-127 = l.
// XOR swizzle byte^=((row&7)<<4): conflict-free ds_read_b128 frags; global_load_lds
// keeps LDS linear, the per-lane GLOBAL source is pre-swizzled (rule 21).
#define BMD 128
#define BND 128
#define CT_PER 16   // col-tiles per split (2048/128)
#define KS_PER 16   // K-steps (512/32)

__global__ __launch_bounds__(256, 2) void dist_kernel(
        const _Float16* __restrict__ xs, const _Float16* __restrict__ es,
        float* __restrict__ ws) {
    __shared__ __align__(16) char As[16384];
    __shared__ __align__(16) char Bs[16384];
    __shared__ float redv1[2][BMD]; __shared__ int redi1[2][BMD];
    __shared__ float redv2[2][BMD]; __shared__ int redi2[2][BMD];

    const int tid = threadIdx.x, wid = tid >> 6, lane = tid & 63;

    // XCD-aware bijective remap: bit0 -> rowblock-half, bits1-2 -> split.
    // With xcd = f%8, each XCD serves one split's blocks (B working set 4.2MB ~ L2).
    int f = blockIdx.x + gridDim.x * blockIdx.y;   // 0..511
    const int split = (f >> 1) & 3;
    const int rb = (f >> 3) + 64 * (f & 1);
    const int rowbase = rb * BMD;
    const int colsplit = split * 2048;

    const int wr = (wid >> 1) * 64, wc = (wid & 1) * 64;
    const int l15 = lane & 15, q = lane >> 4, l7 = lane & 7;

    // frag ds_read offsets (physical, swizzled). comp toggle = ^64.
    const int aoff0 = (wr + l15) * 128 + ((q ^ l7) << 4);
    const int boff0 = (wc + l15) * 128 + ((q ^ l7) << 4);

    // staging: 4 calls/wave each for A and B; physical p = wid*4096 + c*1024 + lane*16
    int gAoff[4], gBoff[4], ldsoff[4];
#pragma unroll
    for (int c = 0; c < 4; ++c) {
        int p = wid * 4096 + c * 1024 + lane * 16;
        int r = p >> 7, b = p & 127;
        int bs = b ^ ((r & 7) << 4);
        int comp = bs >> 6;
        int k8 = (bs >> 4) & 3;
        gAoff[c] = (rowbase + r) * 2048 + comp * 1024 + k8 * 16;     // bytes into Xs
        gBoff[c] = (colsplit + r) * 2048 + comp * 1024 + k8 * 16;    // + kt*262144
        ldsoff[c] = wid * 4096 + c * 1024;                            // wave-uniform base
    }

    float best1[16], best2[16]; int bi1[16], bi2[16];
#pragma unroll
    for (int r = 0; r < 16; ++r) {
        best1[r] = 3.4e38f; best2[r] = 3.4e38f;
        bi1[r] = 0x7fffffff; bi2[r] = 0x7fffffff;
    }

    const char* xb = (const char*)xs;
    const char* eb = (const char*)es;

    for (int kt = 0; kt < CT_PER; ++kt) {
        f32x4 acc[4][4];
#pragma unroll
        for (int m = 0; m < 4; ++m)
#pragma unroll
            for (int n = 0; n < 4; ++n) acc[m][n] = (f32x4){0.f, 0.f, 0.f, 0.f};
        const char* ebt = eb + (size_t)kt * 262144;   // 128 cols * 2048B

        for (int ks = 0; ks < KS_PER; ++ks) {
            __syncthreads();
#pragma unroll
            for (int c = 0; c < 4; ++c) {
                ldg_lds16(xb + gAoff[c] + (ks << 6), As + ldsoff[c]);
                ldg_lds16(ebt + gBoff[c] + (ks << 6), Bs + ldsoff[c]);
            }
            __syncthreads();

            half8 ah[4], al[4], bh[4], bl[4];
#pragma unroll
            for (int m = 0; m < 4; ++m) {
                int o = aoff0 + m * 2048;
                ah[m] = *(const half8*)(As + o);
                al[m] = *(const half8*)(As + (o ^ 64));
            }
#pragma unroll
            for (int n = 0; n < 4; ++n) {
                int o = boff0 + n * 2048;
                bh[n] = *(const half8*)(Bs + o);
                bl[n] = *(const half8*)(Bs + (o ^ 64));
            }
#pragma unroll
            for (int m = 0; m < 4; ++m)
#pragma unroll
                for (int n = 0; n < 4; ++n) {
                    acc[m][n] = __builtin_amdgcn_mfma_f32_16x16x32_f16(ah[m], bh[n], acc[m][n], 0, 0, 0);
                    acc[m][n] = __builtin_amdgcn_mfma_f32_16x16x32_f16(ah[m], bl[n], acc[m][n], 0, 0, 0);
                    acc[m][n] = __builtin_amdgcn_mfma_f32_16x16x32_f16(al[m], bh[n], acc[m][n], 0, 0, 0);
                }
        }

        // epilogue: score = e2[col] - 2*dot; group-min over n, merge into running top-2
        const int cb = colsplit + kt * BND + wc + l15;
        float e2v[4];
#pragma unroll
        for (int n = 0; n < 4; ++n) e2v[n] = ws[WS_E2 + cb + n * 16];
#pragma unroll
        for (int m = 0; m < 4; ++m)
#pragma unroll
            for (int j = 0; j < 4; ++j) {
                int r = m * 4 + j;
                float v0 = fmaf(-2.f, acc[m][0][j], e2v[0]);
                float v1 = fmaf(-2.f, acc[m][1][j], e2v[1]);
                float v2 = fmaf(-2.f, acc[m][2][j], e2v[2]);
                float v3 = fmaf(-2.f, acc[m][3][j], e2v[3]);
                bool t1 = v1 < v0; float m01 = t1 ? v1 : v0; int i01 = t1 ? cb + 16 : cb;
                bool t2 = v3 < v2; float m23 = t2 ? v3 : v2; int i23 = t2 ? cb + 48 : cb + 32;
                bool t3 = m23 < m01; float w = t3 ? m23 : m01; int wi = t3 ? i23 : i01;
                bool a1 = w < best1[r]; bool a2 = w < best2[r];
                best2[r] = a1 ? best1[r] : (a2 ? w : best2[r]);
                bi2[r]   = a1 ? bi1[r]   : (a2 ? wi : bi2[r]);
                best1[r] = a1 ? w : best1[r];
                bi1[r]   = a1 ? wi : bi1[r];
            }
    }

    // butterfly top-2 merge across the 16 col-lanes of each row
#pragma unroll
    for (int mask = 1; mask <= 8; mask <<= 1) {
#pragma unroll
        for (int r = 0; r < 16; ++r) {
            float o1 = __shfl_xor(best1[r], mask); int p1 = __shfl_xor(bi1[r], mask);
            float o2 = __shfl_xor(best2[r], mask); int p2 = __shfl_xor(bi2[r], mask);
            bool t = o1 < best1[r];
            float nb1 = t ? o1 : best1[r]; int ni1 = t ? p1 : bi1[r];
            float hi  = t ? best1[r] : o1; int hii = t ? bi1[r] : p1;
            bool u = o2 < best2[r];
            float lo2 = u ? o2 : best2[r]; int lo2i = u ? p2 : bi2[r];
            bool s = lo2 < hi;
            best2[r] = s ? lo2 : hi; bi2[r] = s ? lo2i : hii;
            best1[r] = nb1; bi1[r] = ni1;
        }
    }
    const int h = wid & 1;
    if (l15 == 0) {
#pragma unroll
        for (int m = 0; m < 4; ++m)
#pragma unroll
            for (int j = 0; j < 4; ++j) {
                int rl = wr + m * 16 + q * 4 + j;
                int r = m * 4 + j;
                redv1[h][rl] = best1[r]; redi1[h][rl] = bi1[r];
                redv2[h][rl] = best2[r]; redi2[h][rl] = bi2[r];
            }
    }
    __syncthreads();
    if (tid < BMD) {
        int r = tid;
        float a1 = redv1[0][r], a2 = redv2[0][r]; int i1 = redi1[0][r], i2 = redi2[0][r];
        float o1 = redv1[1][r], o2 = redv2[1][r]; int j1 = redi1[1][r], j2 = redi2[1][r];
        float b1v, b2v; int c1, c2;
        if (o1 < a1) {
            b1v = o1; c1 = j1;
            bool t = o2 < a1; b2v = t ? o2 : a1; c2 = t ? j2 : i1;
        } else {
            b1v = a1; c1 = i1;
            bool t = o1 < a2; b2v = t ? o1 : a2; c2 = t ? j1 : i2;
        }
        int p = split * N_ROWS + rowbase + r;
        ws[WS_PV1 + p] = b1v; ((int*)ws)[WS_PI1 + p] = c1;
        ws[WS_PV2 + p] = b2v; ((int*)ws)[WS_PI2 + p] = c2;
    }
}

// ====== kernel 2b: fp64 refine of 8 candidates/row -> exact first-min argmin ======
__global__ void refine_kernel(const float* __restrict__ x, const float* __restrict__ embed,
                              float* __restrict__ ws, float* __restrict__ out) {
    int wid = threadIdx.x >> 6, lane = threadIdx.x & 63;
    int row = blockIdx.x * 4 + wid;
    const float* xr = x + row * DIM;
    double bestv = 1e300; int besti = 0x7fffffff;
#pragma unroll
    for (int s = 0; s < 4; ++s) {
#pragma unroll
        for (int t = 0; t < 2; ++t) {
            int ci = ((const int*)ws)[(t ? WS_PI2 : WS_PI1) + s * N_ROWS + row];
            const float* er = embed + ci * DIM;
            double d = 0.0;
#pragma unroll
            for (int u = 0; u < 8; ++u) {
                double diff = (double)xr[lane * 8 + u] - (double)er[lane * 8 + u];
                d += diff * diff;
            }
#pragma unroll
            for (int off = 32; off; off >>= 1) d += __shfl_xor(d, off);
            if (d < bestv || (d == bestv && ci < besti)) { bestv = d; besti = ci; }
        }
    }
    if (lane == 0) {
        ((int*)ws)[WS_IND + row] = besti;
        out[OI + row] = (float)besti;
    }
}

// ===== kernel 3: gather quantize, commit-loss partial, scatter EMA sums =====
__global__ void gather_kernel(const float* __restrict__ x, const float* __restrict__ embed,
                              float* __restrict__ ws, float* __restrict__ out) {
    int tid = threadIdx.x;
    int rl  = tid >> 7;
    int c   = (tid & 127) * 4;
    int row = blockIdx.x * 2 + rl;
    int ind = ((const int*)ws)[WS_IND + row];
    float4 qv = *(const float4*)(embed + ind * DIM + c);
    float4 xv = *(const float4*)(x + row * DIM + c);
    float4 st;
    st.x = xv.x + (qv.x - xv.x); st.y = xv.y + (qv.y - xv.y);
    st.z = xv.z + (qv.z - xv.z); st.w = xv.w + (qv.w - xv.w);
    *(float4*)(out + OQ + row * DIM + c) = st;
    float dx = qv.x - xv.x, dy = qv.y - xv.y, dz = qv.z - xv.z, dw = qv.w - xv.w;
    float s = dx*dx + dy*dy + dz*dz + dw*dw;
#pragma unroll
    for (int off = 32; off; off >>= 1) s += __shfl_xor(s, off);
    __shared__ float ls[4];
    int wid = tid >> 6, lane = tid & 63;
    if (lane == 0) ls[wid] = s;
    __syncthreads();
    if (tid == 0) atomicAdd(ws + WS_LOSS, ls[0] + ls[1] + ls[2] + ls[3]);
    atomicAdd(out + OA + ind * DIM + c + 0, RESIDF * xv.x);
    atomicAdd(out + OA + ind * DIM + c + 1, RESIDF * xv.y);
    atomicAdd(out + OA + ind * DIM + c + 2, RESIDF * xv.z);
    atomicAdd(out + OA + ind * DIM + c + 3, RESIDF * xv.w);
    if ((tid & 127) == 0) atomicAdd(ws + WS_BINS + ind, 1.0f);
}

// ===== kernel 4: new_cluster_size, total reduction, finalize loss =====
__global__ void cluster_kernel(const float* __restrict__ cs, float* __restrict__ ws,
                               float* __restrict__ out) {
    int k = blockIdx.x * 256 + threadIdx.x;
    float ncs = DECAYF * cs[k] + RESIDF * ws[WS_BINS + k];
    out[OC + k] = ncs;
    float s = ncs;
#pragma unroll
    for (int off = 32; off; off >>= 1) s += __shfl_xor(s, off);
    __shared__ float ls[4];
    int wid = threadIdx.x >> 6, lane = threadIdx.x & 63;
    if (lane == 0) ls[wid] = s;
    __syncthreads();
    if (threadIdx.x == 0) atomicAdd(ws + WS_TOTAL, ls[0] + ls[1] + ls[2] + ls[3]);
    if (k == 0) out[OL] = ws[WS_LOSS] / 8388608.0f;
}

// ===== kernel 5: new_embed = new_embed_avg / laplace-smoothed cluster sizes =====
__global__ void finalize_kernel(const float* __restrict__ ws, float* __restrict__ out) {
    int i = blockIdx.x * 256 + threadIdx.x;
    int base = i * 4;
    int k = base >> 9;
    float total = ws[WS_TOTAL];
    float ncs = out[OC + k];
    float sm = (ncs + EPSF) / (total + (float)KCODES * EPSF) * total;
#pragma unroll
    for (int j = 0; j < 4; ++j) {
        float av = out[OA + base + j];
        out[OE + base + j] = av / sm;
    }
}

extern "C" void kernel_launch(void* const* d_in, const int* in_sizes, int n_in,
                              void* d_out, int out_size, void* d_ws, size_t ws_size,
                              hipStream_t stream) {
    const float* x     = (const float*)d_in[0];
    const float* embed = (const float*)d_in[1];
    const float* cs    = (const float*)d_in[2];
    const float* avg   = (const float*)d_in[3];
    float* out = (float*)d_out;
    float* ws  = (float*)d_ws;

    // fp16 scratch tensors live inside d_out (regions rewritten later in the pipeline):
    // Xs fills OQ exactly (33.55 MB); Es fills OE (16B-realigned; <=12B spill into OC,
    // which cluster_kernel rewrites afterwards).
    _Float16* xs = (_Float16*)((char*)d_out + (size_t)OQ * 4);
    _Float16* es = (_Float16*)((char*)d_out + (((size_t)OE * 4 + 15) & ~(size_t)15));

    hipMemsetAsync((char*)d_ws + WS_BINS * 4, 0, (8192 + 2) * 4, stream);

    convx_kernel  <<<4096, 256, 0, stream>>>(x, xs);
    conve_kernel  <<<2048, 256, 0, stream>>>(embed, es);
    e2_kernel     <<<KCODES / 4, 256, 0, stream>>>(embed, ws);
    avginit_kernel<<<4096, 256, 0, stream>>>(avg, out);
    dist_kernel   <<<dim3(128, 4), 256, 0, stream>>>(xs, es, ws);
    refine_kernel <<<N_ROWS / 4, 256, 0, stream>>>(x, embed, ws, out);
    gather_kernel <<<N_ROWS / 2, 256, 0, stream>>>(x, embed, ws, out);
    cluster_kernel<<<KCODES / 256, 256, 0, stream>>>(cs, ws, out);
    finalize_kernel<<<4096, 256, 0, stream>>>(ws, out);
}